// Round 1
// baseline (232.244 us; speedup 1.0000x reference)
//
#include <hip/hip_runtime.h>

// Problem constants (powers of two -> shift/mask index math)
// B=32, C=3, H=512, W=512; H*W = 2^18, W = 2^9
#define IMG_B 32
#define IMG_C 3
#define IMG_H 512
#define IMG_W 512
#define HW_SHIFT 18
#define W_SHIFT 9

// Row-PAIR blocks: each block of 256 threads covers 2 adjacent image rows
// (2 x 512 px); thread t handles the 2x2 set {rows r0,r0+1} x {cols t,t+256}.
// Rationale (R10): gather path is per-dword throughput-bound (~8.5 cyc/dword,
// conserved across repacking, R7/R9). Vertically adjacent pixels share their
// middle corner-row pair (y1-row of px A == y0-row of px B for ~all in-bounds
// pixels of these near-identity warps), so a row-pair thread needs typ. 3
// loaded pairs instead of 4 per column per homography: ~25% fewer dwords.
#define NBLOCKS_X (IMG_H / 2)             // 256 row-pair blocks per image
#define NPARTIALS (NBLOCKS_X * IMG_B)     // 8192 per-block partial sums

// d_ws layout: [0, 2304)         : 64 inverted 3x3 matrices (32 pred, 32 true), 9 floats each
//                                  rows 0/1 pre-scaled by 512/511 (normalization folded in)
//              [2304, 2304+32K)  : per-block float partial sums (no atomics)
#define WS_INV_FLOATS (64 * 9)
#define WS_PART_OFFSET (WS_INV_FLOATS * sizeof(float))

__global__ void photoloss_invert_kernel(const float* __restrict__ Hp,
                                        const float* __restrict__ Ht,
                                        float* __restrict__ ws_inv) {
    int t = threadIdx.x;
    if (t < 64) {
        const float* src = (t < 32) ? (Hp + t * 9) : (Ht + (t - 32) * 9);
        float* dst = ws_inv + t * 9;
        // 3x3 inverse via adjugate, computed in double for conditioning.
        double a = src[0], b = src[1], c = src[2];
        double d = src[3], e = src[4], f = src[5];
        double g = src[6], h = src[7], i = src[8];
        double A = e * i - f * h;
        double Bc = c * h - b * i;
        double Cc = b * f - c * e;
        double D = f * g - d * i;
        double E = a * i - c * g;
        double F = c * d - a * f;
        double G = d * h - e * g;
        double Hh = b * g - a * h;
        double Ii = a * e - b * d;
        double idet = 1.0 / (a * A + b * D + c * G);
        // Fold the grid-normalization chain into rows 0/1:
        // xs = ((2X/(W-1)-1+1)*W-1)*0.5 = X*(W/(W-1)) - 0.5
        const double sc = (double)IMG_W / (double)(IMG_W - 1);  // 512/511 (H==W)
        dst[0] = (float)(A * idet * sc);
        dst[1] = (float)(Bc * idet * sc);
        dst[2] = (float)(Cc * idet * sc);
        dst[3] = (float)(D * idet * sc);
        dst[4] = (float)(E * idet * sc);
        dst[5] = (float)(F * idet * sc);
        dst[6] = (float)(G * idet);
        dst[7] = (float)(Hh * idet);
        dst[8] = (float)(Ii * idet);
    }
}

// Paired-corner sampling setup. The two x-adjacent corners of each bilinear
// row are fetched with ONE 8-byte load (4B-aligned; global loads tolerate
// this on gfx950 -- MUBUF dwordx2 does NOT, which broke R8).
// E[0]/E[1] = clamped element indices of the (y0,y1) row pairs.
// W[0..3]  = weights for (row0.slotA, row0.slotB, row1.slotA, row1.slotB).
// Validity lives ONLY in the weights. Two slot-swap cases:
//  - left edge x0==-1: pair loaded at xc0=0, x1 corner sits in slot A.
//  - clamp-down e==H*W-1 (image corner): x0 corner sits in slot B.
// NOTE: bit-identical arithmetic per pixel regardless of which thread/block
// evaluates it -- row-pair sharing below only de-duplicates LOADS of pairs
// whose element indices already compare equal, so results are unchanged.
__device__ __forceinline__ void grid_setup_pair(float X, float Y, float Z,
                                                int* E, float* W) {
    const float iz = __builtin_amdgcn_rcpf(Z);
    const float xs = __builtin_fmaf(X, iz, -0.5f);
    const float ys = __builtin_fmaf(Y, iz, -0.5f);

    const float x0f = __builtin_floorf(xs);
    const float y0f = __builtin_floorf(ys);
    const int x0 = (int)x0f, y0 = (int)y0f;
    const int x1 = x0 + 1, y1 = y0 + 1;

    float wx1 = xs - x0f, wx0 = 1.0f - wx1;
    float wy1 = ys - y0f, wy0 = 1.0f - wy1;
    const float wx0m = ((unsigned)x0 < (unsigned)IMG_W) ? wx0 : 0.0f;
    const float wx1m = ((unsigned)x1 < (unsigned)IMG_W) ? wx1 : 0.0f;
    const float wy0m = ((unsigned)y0 < (unsigned)IMG_H) ? wy0 : 0.0f;
    const float wy1m = ((unsigned)y1 < (unsigned)IMG_H) ? wy1 : 0.0f;

    const bool sl = (x0 < 0);               // x0==-1 => x1 corner in slot A
    const float xA = sl ? wx1m : wx0m;      // (x0<=-2 => wx1m==0 too)
    const float xB = sl ? 0.0f : wx1m;
    const int xc0 = min(max(x0, 0), IMG_W - 1);

    const int e0r = y0 * IMG_W + xc0;       // may be far out of range
    const int e1r = e0r + IMG_W;
    const int emax = IMG_H * IMG_W - 2;     // pair [emax, emax+1] is last valid
    const int e0 = min(max(e0r, 0), emax);
    const int e1 = min(max(e1r, 0), emax);
    // Clamp fired? Either y-invalid (y-weight 0, slots irrelevant) or the
    // genuine e==H*W-1 corner case (clamp-down by 1: x0 value in slot B).
    const bool d0 = (e0 != e0r);
    const bool d1 = (e1 != e1r);
    const float uA0 = d0 ? 0.0f : xA, uB0 = d0 ? xA : xB;
    const float uA1 = d1 ? 0.0f : xA, uB1 = d1 ? xA : xB;

    E[0] = e0;
    E[1] = e1;
    W[0] = uA0 * wy0m; W[1] = uB0 * wy0m;
    W[2] = uA1 * wy1m; W[3] = uB1 * wy1m;
}

// 8-byte load at 4-byte alignment: memcpy -> load <2 x float> align 4 ->
// global_load_dwordx2 (gfx950 supports unaligned global access).
__device__ __forceinline__ float2 load_pair(const float* p) {
    float2 r;
    __builtin_memcpy(&r, p, 8);
    return r;
}

// 4 px/thread (2 rows x 2 distant cols); __launch_bounds__(256,4) caps VGPR
// at 128 (4 waves/EU).
__global__ __launch_bounds__(256, 4) void photoloss_main_kernel(
        const float* __restrict__ I,
        const float* __restrict__ ws_inv,
        float* __restrict__ partials) {
    const int b = blockIdx.y;
    const int r0 = blockIdx.x * 2;         // row pair (r0, r0+1)
    const int t = threadIdx.x;
    const float fyA = (float)r0;
    const float fyB = (float)(r0 + 1);

    const float* __restrict__ hp = ws_inv + b * 9;          // pred inverse (rows 0/1 pre-scaled)
    const float* __restrict__ ht = ws_inv + (b + 32) * 9;   // true inverse

    // y-dependent part of each homography row, for both image rows.
    const float cxpA = __builtin_fmaf(hp[1], fyA, hp[2]);
    const float cypA = __builtin_fmaf(hp[4], fyA, hp[5]);
    const float czpA = __builtin_fmaf(hp[7], fyA, hp[8]);
    const float cxpB = __builtin_fmaf(hp[1], fyB, hp[2]);
    const float cypB = __builtin_fmaf(hp[4], fyB, hp[5]);
    const float czpB = __builtin_fmaf(hp[7], fyB, hp[8]);
    const float cxtA = __builtin_fmaf(ht[1], fyA, ht[2]);
    const float cytA = __builtin_fmaf(ht[4], fyA, ht[5]);
    const float cztA = __builtin_fmaf(ht[7], fyA, ht[8]);
    const float cxtB = __builtin_fmaf(ht[1], fyB, ht[2]);
    const float cytB = __builtin_fmaf(ht[4], fyB, ht[5]);
    const float cztB = __builtin_fmaf(ht[7], fyB, ht[8]);

    const float hp0 = hp[0], hp3 = hp[3], hp6 = hp[6];
    const float ht0 = ht[0], ht3 = ht[3], ht6 = ht[6];

    const float* __restrict__ ch0 = I + ((size_t)b * IMG_C << HW_SHIFT);
    const float* __restrict__ ch1 = ch0 + ((size_t)1 << HW_SHIFT);
    const float* __restrict__ ch2 = ch0 + ((size_t)2 << HW_SHIFT);

    float lsum = 0.0f;

    for (int cc = 0; cc < 2; ++cc) {
        const float fx = (float)(t + (cc << 8));

        // Per column & homography: setups for both rows.
        // E[0..3] = pred {A.y0, A.y1, B.y0, B.y1}; E[4..7] = true ditto.
        // Wc[0..3]=pred A, [4..7]=pred B, [8..11]=true A, [12..15]=true B.
        int E[8];
        float Wc[16];
        grid_setup_pair(__builtin_fmaf(hp0, fx, cxpA), __builtin_fmaf(hp3, fx, cypA),
                        __builtin_fmaf(hp6, fx, czpA), E + 0, Wc + 0);
        grid_setup_pair(__builtin_fmaf(hp0, fx, cxpB), __builtin_fmaf(hp3, fx, cypB),
                        __builtin_fmaf(hp6, fx, czpB), E + 2, Wc + 4);
        grid_setup_pair(__builtin_fmaf(ht0, fx, cxtA), __builtin_fmaf(ht3, fx, cytA),
                        __builtin_fmaf(ht6, fx, cztA), E + 4, Wc + 8);
        grid_setup_pair(__builtin_fmaf(ht0, fx, cxtB), __builtin_fmaf(ht3, fx, cytB),
                        __builtin_fmaf(ht6, fx, cztB), E + 6, Wc + 12);

        // Vertical sharing: B's y0 pair usually IS A's y1 pair (same element
        // index captures both row alignment and x0 equality; slot bookkeeping
        // lives in the per-pixel weights, the loaded VALUES are identical).
        const bool shp = (E[2] == E[1]);
        const bool sht = (E[6] == E[5]);

        // Pair weight sums (weights are nonneg): >0 means the pair is needed.
        float ps[8];
#pragma unroll
        for (int k = 0; k < 8; ++k) ps[k] = Wc[2 * k] + Wc[2 * k + 1];

        // Load predicates. Slot 1 (A.y1) also serves B.y0 when shared; slot 2
        // (B.y0) loads only on per-lane mismatch. EXEC-masked lanes generate
        // NO TA requests and the gather path is per-dword throughput-bound,
        // so the shared/unneeded pairs cost nothing.
        bool pr[8];
        pr[0] = ps[0] > 0.0f;
        pr[1] = (ps[1] > 0.0f) || (shp && (ps[2] > 0.0f));
        pr[2] = (ps[2] > 0.0f) && !shp;
        pr[3] = ps[3] > 0.0f;
        pr[4] = ps[4] > 0.0f;
        pr[5] = (ps[5] > 0.0f) || (sht && (ps[6] > 0.0f));
        pr[6] = (ps[6] > 0.0f) && !sht;
        pr[7] = ps[7] > 0.0f;

        // Batch the (predicated) paired loads; one predicate serves all 3
        // channels, so 8 exec-toggles guard 24 loads.
        float2 r[24];
#pragma unroll
        for (int j = 0; j < 8; ++j) {
            float2 v0 = make_float2(0.0f, 0.0f);
            float2 v1 = v0;
            float2 v2 = v0;
            if (pr[j]) {
                v0 = load_pair(ch0 + E[j]);
                v1 = load_pair(ch1 + E[j]);
                v2 = load_pair(ch2 + E[j]);
            }
            r[0 * 8 + j] = v0;
            r[1 * 8 + j] = v1;
            r[2 * 8 + j] = v2;
        }

#pragma unroll
        for (int c = 0; c < IMG_C; ++c) {
            const float2* rc = r + c * 8;
            const float2 pb0 = shp ? rc[1] : rc[2];   // B.y0 values (2 cndmask)
            const float2 tb0 = sht ? rc[5] : rc[6];
            const float spA = rc[0].x * Wc[0]  + rc[0].y * Wc[1]  + rc[1].x * Wc[2]  + rc[1].y * Wc[3];
            const float spB = pb0.x   * Wc[4]  + pb0.y   * Wc[5]  + rc[3].x * Wc[6]  + rc[3].y * Wc[7];
            const float stA = rc[4].x * Wc[8]  + rc[4].y * Wc[9]  + rc[5].x * Wc[10] + rc[5].y * Wc[11];
            const float stB = tb0.x   * Wc[12] + tb0.y   * Wc[13] + rc[7].x * Wc[14] + rc[7].y * Wc[15];
            const float dA = spA - stA;
            const float dB = spB - stB;
            lsum = __builtin_fmaf(dA, dA, lsum);
            lsum = __builtin_fmaf(dB, dB, lsum);
        }
    }

    // wave (64-lane) reduction
#pragma unroll
    for (int off = 32; off > 0; off >>= 1)
        lsum += __shfl_down(lsum, off, 64);

    __shared__ float wsum[4];
    const int lane = threadIdx.x & 63;
    const int wid = threadIdx.x >> 6;
    if (lane == 0) wsum[wid] = lsum;
    __syncthreads();
    if (threadIdx.x == 0) {
        // One coalesced store per block -- NO atomics (same-address fp64
        // atomicAdd serialized the whole grid at ~400 us in R1/R2).
        partials[blockIdx.y * gridDim.x + blockIdx.x] = wsum[0] + wsum[1] + wsum[2] + wsum[3];
    }
}

__global__ __launch_bounds__(1024) void photoloss_reduce_kernel(
        const float* __restrict__ partials, float* __restrict__ out) {
    // Single block, 1024 threads = 16 waves; 8 partials per thread.
    double s = 0.0;
    for (int i = threadIdx.x; i < NPARTIALS; i += 1024)
        s += (double)partials[i];
#pragma unroll
    for (int off = 32; off > 0; off >>= 1)
        s += __shfl_down(s, off, 64);

    __shared__ double wsum[16];
    const int lane = threadIdx.x & 63;
    const int wid = threadIdx.x >> 6;
    if (lane == 0) wsum[wid] = s;
    __syncthreads();
    if (threadIdx.x == 0) {
        double total = 0.0;
#pragma unroll
        for (int i = 0; i < 16; ++i) total += wsum[i];
        const double n = (double)IMG_B * IMG_C * IMG_H * IMG_W;  // 25165824
        out[0] = (float)(total / n);
    }
}

extern "C" void kernel_launch(void* const* d_in, const int* in_sizes, int n_in,
                              void* d_out, int out_size, void* d_ws, size_t ws_size,
                              hipStream_t stream) {
    const float* Hp = (const float*)d_in[0];
    const float* Ht = (const float*)d_in[1];
    const float* I  = (const float*)d_in[2];
    float* out = (float*)d_out;

    float* ws_inv = (float*)d_ws;
    float* partials = (float*)((char*)d_ws + WS_PART_OFFSET);

    photoloss_invert_kernel<<<1, 64, 0, stream>>>(Hp, Ht, ws_inv);

    dim3 grid(NBLOCKS_X, IMG_B);  // (256, 32), natural order (R6 XCD swizzle regressed)
    photoloss_main_kernel<<<grid, 256, 0, stream>>>(I, ws_inv, partials);

    photoloss_reduce_kernel<<<1, 1024, 0, stream>>>(partials, out);
}

// Round 2
// 205.355 us; speedup vs baseline: 1.1309x; 1.1309x over previous
//
#include <hip/hip_runtime.h>

// Problem constants (powers of two -> shift/mask index math)
// B=32, C=3, H=512, W=512; H*W = 2^18, W = 2^9
#define IMG_B 32
#define IMG_C 3
#define IMG_H 512
#define IMG_W 512
#define HW_SHIFT 18
#define W_SHIFT 9

// R11: vertical-pair threads at FULL parallelism.
// R10 post-mortem: row-pair blocks (4 px/thread, serial column loop) halved
// TLP and serialized the load batches -> 63->106us, VALUBusy 60->35%.
// The sharing idea survives; the parallelism structure must match R9:
//   - 256-thread blocks, grid (512, 32) = (row-pair x col-half, batch)
//   - 2 px/thread, ONE batched predicated load flight
//   - but the 2 px are now (x, r0) and (x, r0+1): their middle corner-row
//     pair (A.y1 == B.y0 element index) is loaded once when equal, which is
//     ~always for these near-identity warps => typ. 18 float2 loads (36
//     dwords) instead of 24 (48) on the per-dword-throughput-bound gather.
#define NBLOCKS_X IMG_H                   // 256 row-pairs x 2 col-halves
#define NPARTIALS (NBLOCKS_X * IMG_B)     // 16384 per-block partial sums

// d_ws layout: [0, 2304)         : 64 inverted 3x3 matrices (32 pred, 32 true), 9 floats each
//                                  rows 0/1 pre-scaled by 512/511 (normalization folded in)
//              [2304, 2304+64K)  : per-block float partial sums (no atomics)
#define WS_INV_FLOATS (64 * 9)
#define WS_PART_OFFSET (WS_INV_FLOATS * sizeof(float))

__global__ void photoloss_invert_kernel(const float* __restrict__ Hp,
                                        const float* __restrict__ Ht,
                                        float* __restrict__ ws_inv) {
    int t = threadIdx.x;
    if (t < 64) {
        const float* src = (t < 32) ? (Hp + t * 9) : (Ht + (t - 32) * 9);
        float* dst = ws_inv + t * 9;
        // 3x3 inverse via adjugate, computed in double for conditioning.
        double a = src[0], b = src[1], c = src[2];
        double d = src[3], e = src[4], f = src[5];
        double g = src[6], h = src[7], i = src[8];
        double A = e * i - f * h;
        double Bc = c * h - b * i;
        double Cc = b * f - c * e;
        double D = f * g - d * i;
        double E = a * i - c * g;
        double F = c * d - a * f;
        double G = d * h - e * g;
        double Hh = b * g - a * h;
        double Ii = a * e - b * d;
        double idet = 1.0 / (a * A + b * D + c * G);
        // Fold the grid-normalization chain into rows 0/1:
        // xs = ((2X/(W-1)-1+1)*W-1)*0.5 = X*(W/(W-1)) - 0.5
        const double sc = (double)IMG_W / (double)(IMG_W - 1);  // 512/511 (H==W)
        dst[0] = (float)(A * idet * sc);
        dst[1] = (float)(Bc * idet * sc);
        dst[2] = (float)(Cc * idet * sc);
        dst[3] = (float)(D * idet * sc);
        dst[4] = (float)(E * idet * sc);
        dst[5] = (float)(F * idet * sc);
        dst[6] = (float)(G * idet);
        dst[7] = (float)(Hh * idet);
        dst[8] = (float)(Ii * idet);
    }
}

// Paired-corner sampling setup. The two x-adjacent corners of each bilinear
// row are fetched with ONE 8-byte load (4B-aligned; global loads tolerate
// this on gfx950 -- MUBUF dwordx2 does NOT, which broke R8).
// E[0]/E[1] = clamped element indices of the (y0,y1) row pairs.
// W[0..3]  = weights for (row0.slotA, row0.slotB, row1.slotA, row1.slotB).
// Validity lives ONLY in the weights. Two slot-swap cases:
//  - left edge x0==-1: pair loaded at xc0=0, x1 corner sits in slot A.
//  - clamp-down e==H*W-1 (image corner): x0 corner sits in slot B.
// NOTE: bit-identical arithmetic per pixel regardless of which thread/block
// evaluates it -- vertical sharing below only de-duplicates LOADS of pairs
// whose element indices already compare equal, so results are unchanged.
__device__ __forceinline__ void grid_setup_pair(float X, float Y, float Z,
                                                int* E, float* W) {
    const float iz = __builtin_amdgcn_rcpf(Z);
    const float xs = __builtin_fmaf(X, iz, -0.5f);
    const float ys = __builtin_fmaf(Y, iz, -0.5f);

    const float x0f = __builtin_floorf(xs);
    const float y0f = __builtin_floorf(ys);
    const int x0 = (int)x0f, y0 = (int)y0f;
    const int x1 = x0 + 1, y1 = y0 + 1;

    float wx1 = xs - x0f, wx0 = 1.0f - wx1;
    float wy1 = ys - y0f, wy0 = 1.0f - wy1;
    const float wx0m = ((unsigned)x0 < (unsigned)IMG_W) ? wx0 : 0.0f;
    const float wx1m = ((unsigned)x1 < (unsigned)IMG_W) ? wx1 : 0.0f;
    const float wy0m = ((unsigned)y0 < (unsigned)IMG_H) ? wy0 : 0.0f;
    const float wy1m = ((unsigned)y1 < (unsigned)IMG_H) ? wy1 : 0.0f;

    const bool sl = (x0 < 0);               // x0==-1 => x1 corner in slot A
    const float xA = sl ? wx1m : wx0m;      // (x0<=-2 => wx1m==0 too)
    const float xB = sl ? 0.0f : wx1m;
    const int xc0 = min(max(x0, 0), IMG_W - 1);

    const int e0r = y0 * IMG_W + xc0;       // may be far out of range
    const int e1r = e0r + IMG_W;
    const int emax = IMG_H * IMG_W - 2;     // pair [emax, emax+1] is last valid
    const int e0 = min(max(e0r, 0), emax);
    const int e1 = min(max(e1r, 0), emax);
    // Clamp fired? Either y-invalid (y-weight 0, slots irrelevant) or the
    // genuine e==H*W-1 corner case (clamp-down by 1: x0 value in slot B).
    const bool d0 = (e0 != e0r);
    const bool d1 = (e1 != e1r);
    const float uA0 = d0 ? 0.0f : xA, uB0 = d0 ? xA : xB;
    const float uA1 = d1 ? 0.0f : xA, uB1 = d1 ? xA : xB;

    E[0] = e0;
    E[1] = e1;
    W[0] = uA0 * wy0m; W[1] = uB0 * wy0m;
    W[2] = uA1 * wy1m; W[3] = uB1 * wy1m;
}

// 8-byte load at 4-byte alignment: memcpy -> load <2 x float> align 4 ->
// global_load_dwordx2 (gfx950 supports unaligned global access).
__device__ __forceinline__ float2 load_pair(const float* p) {
    float2 r;
    __builtin_memcpy(&r, p, 8);
    return r;
}

// 2 px/thread (vertical pair); __launch_bounds__(256,4) caps VGPR at 128.
__global__ __launch_bounds__(256, 4) void photoloss_main_kernel(
        const float* __restrict__ I,
        const float* __restrict__ ws_inv,
        float* __restrict__ partials) {
    const int b = blockIdx.y;
    const int rp = blockIdx.x >> 1;        // row pair index
    const int colh = blockIdx.x & 1;       // column half
    const int r0 = rp * 2;
    const int t = threadIdx.x;
    const float fx = (float)(t + (colh << 8));
    const float fyA = (float)r0;
    const float fyB = (float)(r0 + 1);

    const float* __restrict__ hp = ws_inv + b * 9;          // pred inverse (rows 0/1 pre-scaled)
    const float* __restrict__ ht = ws_inv + (b + 32) * 9;   // true inverse

    // y-dependent part of each homography row, for both image rows.
    const float cxpA = __builtin_fmaf(hp[1], fyA, hp[2]);
    const float cypA = __builtin_fmaf(hp[4], fyA, hp[5]);
    const float czpA = __builtin_fmaf(hp[7], fyA, hp[8]);
    const float cxpB = __builtin_fmaf(hp[1], fyB, hp[2]);
    const float cypB = __builtin_fmaf(hp[4], fyB, hp[5]);
    const float czpB = __builtin_fmaf(hp[7], fyB, hp[8]);
    const float cxtA = __builtin_fmaf(ht[1], fyA, ht[2]);
    const float cytA = __builtin_fmaf(ht[4], fyA, ht[5]);
    const float cztA = __builtin_fmaf(ht[7], fyA, ht[8]);
    const float cxtB = __builtin_fmaf(ht[1], fyB, ht[2]);
    const float cytB = __builtin_fmaf(ht[4], fyB, ht[5]);
    const float cztB = __builtin_fmaf(ht[7], fyB, ht[8]);

    // Per column & homography: setups for both rows.
    // E[0..3] = pred {A.y0, A.y1, B.y0, B.y1}; E[4..7] = true ditto.
    // Wc[0..3]=pred A, [4..7]=pred B, [8..11]=true A, [12..15]=true B.
    int E[8];
    float Wc[16];
    grid_setup_pair(__builtin_fmaf(hp[0], fx, cxpA), __builtin_fmaf(hp[3], fx, cypA),
                    __builtin_fmaf(hp[6], fx, czpA), E + 0, Wc + 0);
    grid_setup_pair(__builtin_fmaf(hp[0], fx, cxpB), __builtin_fmaf(hp[3], fx, cypB),
                    __builtin_fmaf(hp[6], fx, czpB), E + 2, Wc + 4);
    grid_setup_pair(__builtin_fmaf(ht[0], fx, cxtA), __builtin_fmaf(ht[3], fx, cytA),
                    __builtin_fmaf(ht[6], fx, cztA), E + 4, Wc + 8);
    grid_setup_pair(__builtin_fmaf(ht[0], fx, cxtB), __builtin_fmaf(ht[3], fx, cytB),
                    __builtin_fmaf(ht[6], fx, cztB), E + 6, Wc + 12);

    // Vertical sharing: B's y0 pair usually IS A's y1 pair (element-index
    // equality is exact: captures row alignment AND x0 equality; slot
    // bookkeeping lives in the per-pixel weights, loaded VALUES identical).
    const bool shp = (E[2] == E[1]);
    const bool sht = (E[6] == E[5]);

    // Pair weight sums (weights are nonneg): >0 means the pair is needed.
    float ps[8];
#pragma unroll
    for (int k = 0; k < 8; ++k) ps[k] = Wc[2 * k] + Wc[2 * k + 1];

    // Load predicates. Slot 1 (A.y1) also serves B.y0 when shared; slot 2
    // (B.y0) loads only on per-lane mismatch. EXEC-masked lanes generate NO
    // TA requests and the gather path is per-dword throughput-bound (R7/R9),
    // so shared/unneeded pairs cost ~nothing.
    bool pr[8];
    pr[0] = ps[0] > 0.0f;
    pr[1] = (ps[1] > 0.0f) || (shp && (ps[2] > 0.0f));
    pr[2] = (ps[2] > 0.0f) && !shp;
    pr[3] = ps[3] > 0.0f;
    pr[4] = ps[4] > 0.0f;
    pr[5] = (ps[5] > 0.0f) || (sht && (ps[6] > 0.0f));
    pr[6] = (ps[6] > 0.0f) && !sht;
    pr[7] = ps[7] > 0.0f;

    const float* __restrict__ ch0 = I + ((size_t)b * IMG_C << HW_SHIFT);
    const float* __restrict__ ch1 = ch0 + ((size_t)1 << HW_SHIFT);
    const float* __restrict__ ch2 = ch0 + ((size_t)2 << HW_SHIFT);

    // ONE batched predicated load flight (as R9); one predicate serves all 3
    // channels, so 8 exec-toggles guard 24 loads.
    float2 r[24];
#pragma unroll
    for (int j = 0; j < 8; ++j) {
        float2 v0 = make_float2(0.0f, 0.0f);
        float2 v1 = v0;
        float2 v2 = v0;
        if (pr[j]) {
            v0 = load_pair(ch0 + E[j]);
            v1 = load_pair(ch1 + E[j]);
            v2 = load_pair(ch2 + E[j]);
        }
        r[0 * 8 + j] = v0;
        r[1 * 8 + j] = v1;
        r[2 * 8 + j] = v2;
    }

    float lsum = 0.0f;
#pragma unroll
    for (int c = 0; c < IMG_C; ++c) {
        const float2* rc = r + c * 8;
        const float2 pb0 = shp ? rc[1] : rc[2];   // B.y0 values (2 cndmask)
        const float2 tb0 = sht ? rc[5] : rc[6];
        const float spA = rc[0].x * Wc[0]  + rc[0].y * Wc[1]  + rc[1].x * Wc[2]  + rc[1].y * Wc[3];
        const float spB = pb0.x   * Wc[4]  + pb0.y   * Wc[5]  + rc[3].x * Wc[6]  + rc[3].y * Wc[7];
        const float stA = rc[4].x * Wc[8]  + rc[4].y * Wc[9]  + rc[5].x * Wc[10] + rc[5].y * Wc[11];
        const float stB = tb0.x   * Wc[12] + tb0.y   * Wc[13] + rc[7].x * Wc[14] + rc[7].y * Wc[15];
        const float dA = spA - stA;
        const float dB = spB - stB;
        lsum = __builtin_fmaf(dA, dA, lsum);
        lsum = __builtin_fmaf(dB, dB, lsum);
    }

    // wave (64-lane) reduction
#pragma unroll
    for (int off = 32; off > 0; off >>= 1)
        lsum += __shfl_down(lsum, off, 64);

    __shared__ float wsum[4];
    const int lane = threadIdx.x & 63;
    const int wid = threadIdx.x >> 6;
    if (lane == 0) wsum[wid] = lsum;
    __syncthreads();
    if (threadIdx.x == 0) {
        // One coalesced store per block -- NO atomics (same-address fp64
        // atomicAdd serialized the whole grid at ~400 us in R1/R2).
        partials[blockIdx.y * gridDim.x + blockIdx.x] = wsum[0] + wsum[1] + wsum[2] + wsum[3];
    }
}

__global__ __launch_bounds__(1024) void photoloss_reduce_kernel(
        const float* __restrict__ partials, float* __restrict__ out) {
    // Single block, 1024 threads = 16 waves; 16 partials per thread.
    double s = 0.0;
    for (int i = threadIdx.x; i < NPARTIALS; i += 1024)
        s += (double)partials[i];
#pragma unroll
    for (int off = 32; off > 0; off >>= 1)
        s += __shfl_down(s, off, 64);

    __shared__ double wsum[16];
    const int lane = threadIdx.x & 63;
    const int wid = threadIdx.x >> 6;
    if (lane == 0) wsum[wid] = s;
    __syncthreads();
    if (threadIdx.x == 0) {
        double total = 0.0;
#pragma unroll
        for (int i = 0; i < 16; ++i) total += wsum[i];
        const double n = (double)IMG_B * IMG_C * IMG_H * IMG_W;  // 25165824
        out[0] = (float)(total / n);
    }
}

extern "C" void kernel_launch(void* const* d_in, const int* in_sizes, int n_in,
                              void* d_out, int out_size, void* d_ws, size_t ws_size,
                              hipStream_t stream) {
    const float* Hp = (const float*)d_in[0];
    const float* Ht = (const float*)d_in[1];
    const float* I  = (const float*)d_in[2];
    float* out = (float*)d_out;

    float* ws_inv = (float*)d_ws;
    float* partials = (float*)((char*)d_ws + WS_PART_OFFSET);

    photoloss_invert_kernel<<<1, 64, 0, stream>>>(Hp, Ht, ws_inv);

    dim3 grid(NBLOCKS_X, IMG_B);  // (512, 32), natural order (R6 XCD swizzle regressed)
    photoloss_main_kernel<<<grid, 256, 0, stream>>>(I, ws_inv, partials);

    photoloss_reduce_kernel<<<1, 1024, 0, stream>>>(partials, out);
}

// Round 4
// 189.455 us; speedup vs baseline: 1.2259x; 1.0839x over previous
//
#include <hip/hip_runtime.h>

// Problem constants (powers of two -> shift/mask index math)
// B=32, C=3, H=512, W=512; H*W = 2^18, W = 2^9
#define IMG_B 32
#define IMG_C 3
#define IMG_H 512
#define IMG_W 512
#define HW_SHIFT 18
#define W_SHIFT 9

// R12 (resubmit after infra failure -- container died, no counters came
// back; kernel experiment is unchanged):
// 1 px/thread, 512-thread blocks (one full image row per block).
// R10/R11 post-mortem: BOTH dword-sharing structures were slower than R9
// despite fewer requested dwords (R11: -25% dwords, FETCH 52->35MB, yet
// 63->78us) => the gather is NOT per-dword bound at the margin; R9 is
// LATENCY-bound (VALUBusy 60%, occupancy 53%, no pipe saturated).
// Lever: halve the per-wave dependency chain (12 gather loads/wave instead
// of 24, half the setup VALU before the vmcnt drain) and double the waves
// per dispatched block (8/block). Per-pixel math is bit-identical to R9;
// only the reduction tree order changes (~1 ulp on the final scalar).
// Tweak vs first R12 attempt: __launch_bounds__(512) without the ",8"
// min-waves hint -- the hard 64-VGPR cap could force spills; expected
// natural allocation is ~40 VGPR which yields 8 waves/SIMD anyway.
#define NBLOCKS_X IMG_H                   // 512 row-blocks per image
#define NPARTIALS (NBLOCKS_X * IMG_B)     // 16384 per-block partial sums

// d_ws layout: [0, 2304)         : 64 inverted 3x3 matrices (32 pred, 32 true), 9 floats each
//                                  rows 0/1 pre-scaled by 512/511 (normalization folded in)
//              [2304, 2304+64K)  : per-block float partial sums (no atomics)
#define WS_INV_FLOATS (64 * 9)
#define WS_PART_OFFSET (WS_INV_FLOATS * sizeof(float))

__global__ void photoloss_invert_kernel(const float* __restrict__ Hp,
                                        const float* __restrict__ Ht,
                                        float* __restrict__ ws_inv) {
    int t = threadIdx.x;
    if (t < 64) {
        const float* src = (t < 32) ? (Hp + t * 9) : (Ht + (t - 32) * 9);
        float* dst = ws_inv + t * 9;
        // 3x3 inverse via adjugate, computed in double for conditioning.
        double a = src[0], b = src[1], c = src[2];
        double d = src[3], e = src[4], f = src[5];
        double g = src[6], h = src[7], i = src[8];
        double A = e * i - f * h;
        double Bc = c * h - b * i;
        double Cc = b * f - c * e;
        double D = f * g - d * i;
        double E = a * i - c * g;
        double F = c * d - a * f;
        double G = d * h - e * g;
        double Hh = b * g - a * h;
        double Ii = a * e - b * d;
        double idet = 1.0 / (a * A + b * D + c * G);
        // Fold the grid-normalization chain into rows 0/1:
        // xs = ((2X/(W-1)-1+1)*W-1)*0.5 = X*(W/(W-1)) - 0.5
        const double sc = (double)IMG_W / (double)(IMG_W - 1);  // 512/511 (H==W)
        dst[0] = (float)(A * idet * sc);
        dst[1] = (float)(Bc * idet * sc);
        dst[2] = (float)(Cc * idet * sc);
        dst[3] = (float)(D * idet * sc);
        dst[4] = (float)(E * idet * sc);
        dst[5] = (float)(F * idet * sc);
        dst[6] = (float)(G * idet);
        dst[7] = (float)(Hh * idet);
        dst[8] = (float)(Ii * idet);
    }
}

// Paired-corner sampling setup. The two x-adjacent corners of each bilinear
// row are fetched with ONE 8-byte load (4B-aligned; global loads tolerate
// this on gfx950 -- MUBUF dwordx2 does NOT, which broke R8).
// E[0]/E[1] = clamped element indices of the (y0,y1) row pairs.
// W[0..3]  = weights for (row0.slotA, row0.slotB, row1.slotA, row1.slotB).
// Validity lives ONLY in the weights. Two slot-swap cases:
//  - left edge x0==-1: pair loaded at xc0=0, x1 corner sits in slot A.
//  - clamp-down e==H*W-1 (image corner): x0 corner sits in slot B.
__device__ __forceinline__ void grid_setup_pair(float X, float Y, float Z,
                                                int* E, float* W) {
    const float iz = __builtin_amdgcn_rcpf(Z);
    const float xs = __builtin_fmaf(X, iz, -0.5f);
    const float ys = __builtin_fmaf(Y, iz, -0.5f);

    const float x0f = __builtin_floorf(xs);
    const float y0f = __builtin_floorf(ys);
    const int x0 = (int)x0f, y0 = (int)y0f;
    const int x1 = x0 + 1, y1 = y0 + 1;

    float wx1 = xs - x0f, wx0 = 1.0f - wx1;
    float wy1 = ys - y0f, wy0 = 1.0f - wy1;
    const float wx0m = ((unsigned)x0 < (unsigned)IMG_W) ? wx0 : 0.0f;
    const float wx1m = ((unsigned)x1 < (unsigned)IMG_W) ? wx1 : 0.0f;
    const float wy0m = ((unsigned)y0 < (unsigned)IMG_H) ? wy0 : 0.0f;
    const float wy1m = ((unsigned)y1 < (unsigned)IMG_H) ? wy1 : 0.0f;

    const bool sl = (x0 < 0);               // x0==-1 => x1 corner in slot A
    const float xA = sl ? wx1m : wx0m;      // (x0<=-2 => wx1m==0 too)
    const float xB = sl ? 0.0f : wx1m;
    const int xc0 = min(max(x0, 0), IMG_W - 1);

    const int e0r = y0 * IMG_W + xc0;       // may be far out of range
    const int e1r = e0r + IMG_W;
    const int emax = IMG_H * IMG_W - 2;     // pair [emax, emax+1] is last valid
    const int e0 = min(max(e0r, 0), emax);
    const int e1 = min(max(e1r, 0), emax);
    // Clamp fired? Either y-invalid (y-weight 0, slots irrelevant) or the
    // genuine e==H*W-1 corner case (clamp-down by 1: x0 value in slot B).
    const bool d0 = (e0 != e0r);
    const bool d1 = (e1 != e1r);
    const float uA0 = d0 ? 0.0f : xA, uB0 = d0 ? xA : xB;
    const float uA1 = d1 ? 0.0f : xA, uB1 = d1 ? xA : xB;

    E[0] = e0;
    E[1] = e1;
    W[0] = uA0 * wy0m; W[1] = uB0 * wy0m;
    W[2] = uA1 * wy1m; W[3] = uB1 * wy1m;
}

// 8-byte load at 4-byte alignment: memcpy -> load <2 x float> align 4 ->
// global_load_dwordx2 (gfx950 supports unaligned global access).
__device__ __forceinline__ float2 load_pair(const float* p) {
    float2 r;
    __builtin_memcpy(&r, p, 8);
    return r;
}

// 1 px/thread, one image row per 512-thread block.
__global__ __launch_bounds__(512) void photoloss_main_kernel(
        const float* __restrict__ I,
        const float* __restrict__ ws_inv,
        float* __restrict__ partials) {
    const int b = blockIdx.y;
    const int row = blockIdx.x;            // one full image row per block
    const int t = threadIdx.x;             // = x
    const float fy = (float)row;
    const float fx = (float)t;

    const float* __restrict__ hp = ws_inv + b * 9;          // pred inverse (rows 0/1 pre-scaled)
    const float* __restrict__ ht = ws_inv + (b + 32) * 9;   // true inverse

    // y-dependent part of each homography row
    const float cxp = __builtin_fmaf(hp[1], fy, hp[2]);
    const float cyp = __builtin_fmaf(hp[4], fy, hp[5]);
    const float czp = __builtin_fmaf(hp[7], fy, hp[8]);
    const float cxt = __builtin_fmaf(ht[1], fy, ht[2]);
    const float cyt = __builtin_fmaf(ht[4], fy, ht[5]);
    const float czt = __builtin_fmaf(ht[7], fy, ht[8]);

    // Pairs: j=0 pred.y0, j=1 pred.y1 (Wc[0..3]); j=2 true.y0, j=3 true.y1
    // (Wc[4..7]).
    int E[4];
    float Wc[8];
    grid_setup_pair(__builtin_fmaf(hp[0], fx, cxp), __builtin_fmaf(hp[3], fx, cyp),
                    __builtin_fmaf(hp[6], fx, czp), E + 0, Wc + 0);
    grid_setup_pair(__builtin_fmaf(ht[0], fx, cxt), __builtin_fmaf(ht[3], fx, cyt),
                    __builtin_fmaf(ht[6], fx, czt), E + 2, Wc + 4);

    // Per-pair predicate (weights nonneg; sum==0 => pair contributes v*0
    // only -> skip its loads; EXEC-masked lanes generate NO TA requests).
    bool pr[4];
#pragma unroll
    for (int k = 0; k < 4; ++k)
        pr[k] = (Wc[2 * k] + Wc[2 * k + 1]) > 0.0f;

    const float* __restrict__ ch0 = I + ((size_t)b * IMG_C << HW_SHIFT);
    const float* __restrict__ ch1 = ch0 + ((size_t)1 << HW_SHIFT);
    const float* __restrict__ ch2 = ch0 + ((size_t)2 << HW_SHIFT);

    // ONE batched predicated load flight; one predicate serves all 3
    // channels, so 4 exec-toggles guard 12 loads.
    float2 r[12];
#pragma unroll
    for (int j = 0; j < 4; ++j) {
        float2 v0 = make_float2(0.0f, 0.0f);
        float2 v1 = v0;
        float2 v2 = v0;
        if (pr[j]) {
            v0 = load_pair(ch0 + E[j]);
            v1 = load_pair(ch1 + E[j]);
            v2 = load_pair(ch2 + E[j]);
        }
        r[0 * 4 + j] = v0;
        r[1 * 4 + j] = v1;
        r[2 * 4 + j] = v2;
    }

    float lsum = 0.0f;
#pragma unroll
    for (int c = 0; c < IMG_C; ++c) {
        const float2* rc = r + c * 4;
        const float sp = rc[0].x * Wc[0] + rc[0].y * Wc[1] + rc[1].x * Wc[2] + rc[1].y * Wc[3];
        const float st = rc[2].x * Wc[4] + rc[2].y * Wc[5] + rc[3].x * Wc[6] + rc[3].y * Wc[7];
        const float d = sp - st;
        lsum = __builtin_fmaf(d, d, lsum);
    }

    // wave (64-lane) reduction
#pragma unroll
    for (int off = 32; off > 0; off >>= 1)
        lsum += __shfl_down(lsum, off, 64);

    __shared__ float wsum[8];
    const int lane = threadIdx.x & 63;
    const int wid = threadIdx.x >> 6;
    if (lane == 0) wsum[wid] = lsum;
    __syncthreads();
    if (threadIdx.x == 0) {
        // One coalesced store per block -- NO atomics (same-address fp64
        // atomicAdd serialized the whole grid at ~400 us in R1/R2).
        float s = 0.0f;
#pragma unroll
        for (int i = 0; i < 8; ++i) s += wsum[i];
        partials[blockIdx.y * gridDim.x + blockIdx.x] = s;
    }
}

__global__ __launch_bounds__(1024) void photoloss_reduce_kernel(
        const float* __restrict__ partials, float* __restrict__ out) {
    // Single block, 1024 threads = 16 waves; 16 partials per thread.
    double s = 0.0;
    for (int i = threadIdx.x; i < NPARTIALS; i += 1024)
        s += (double)partials[i];
#pragma unroll
    for (int off = 32; off > 0; off >>= 1)
        s += __shfl_down(s, off, 64);

    __shared__ double wsum[16];
    const int lane = threadIdx.x & 63;
    const int wid = threadIdx.x >> 6;
    if (lane == 0) wsum[wid] = s;
    __syncthreads();
    if (threadIdx.x == 0) {
        double total = 0.0;
#pragma unroll
        for (int i = 0; i < 16; ++i) total += wsum[i];
        const double n = (double)IMG_B * IMG_C * IMG_H * IMG_W;  // 25165824
        out[0] = (float)(total / n);
    }
}

extern "C" void kernel_launch(void* const* d_in, const int* in_sizes, int n_in,
                              void* d_out, int out_size, void* d_ws, size_t ws_size,
                              hipStream_t stream) {
    const float* Hp = (const float*)d_in[0];
    const float* Ht = (const float*)d_in[1];
    const float* I  = (const float*)d_in[2];
    float* out = (float*)d_out;

    float* ws_inv = (float*)d_ws;
    float* partials = (float*)((char*)d_ws + WS_PART_OFFSET);

    photoloss_invert_kernel<<<1, 64, 0, stream>>>(Hp, Ht, ws_inv);

    dim3 grid(NBLOCKS_X, IMG_B);  // (512, 32), natural order (R6 XCD swizzle regressed)
    photoloss_main_kernel<<<grid, 512, 0, stream>>>(I, ws_inv, partials);

    photoloss_reduce_kernel<<<1, 1024, 0, stream>>>(partials, out);
}

// Round 5
// 189.165 us; speedup vs baseline: 1.2277x; 1.0015x over previous
//
#include <hip/hip_runtime.h>

// Problem constants (powers of two -> shift/mask index math)
// B=32, C=3, H=512, W=512; H*W = 2^18, W = 2^9
#define IMG_B 32
#define IMG_C 3
#define IMG_H 512
#define IMG_W 512
#define HW_SHIFT 18
#define W_SHIFT 9

// R13: wave-uniform interior fast path on top of R12.
// Evidence matrix: R11 (-25% dwords) -> SLOWER; R12 (occupancy 53->67%,
// half dep-chain) -> FLAT. Memory-request count and latency-hiding are both
// falsified as the marginal bottleneck. VALUBusy (60-66%) is the highest
// measured utilization -> last visible lever is VALU count, tested with
// memory work held EXACTLY constant (same load instrs, same dwords).
// A wave whose 64 lanes are all interior (x0 in [0,510], y0 in [0,510] for
// BOTH homographies) can skip all edge machinery: no weight masks, no slot
// swaps, no index clamps, no per-pair predicates, no exec toggles; weights
// are the raw bilinear products in identical op order (bit-identical
// output); E0=(y0<<9)+x0, E1=E0+512 provably in [0, H*W-2] so unconditional
// paired loads are safe (exact-zero weights null any loaded value).
// Edge/OOB waves run the R12 path verbatim (incl. OOB load skipping).
#define NBLOCKS_X IMG_H                   // 512 row-blocks per image
#define NPARTIALS (NBLOCKS_X * IMG_B)     // 16384 per-block partial sums

// d_ws layout: [0, 2304)         : 64 inverted 3x3 matrices (32 pred, 32 true), 9 floats each
//                                  rows 0/1 pre-scaled by 512/511 (normalization folded in)
//              [2304, 2304+64K)  : per-block float partial sums (no atomics)
#define WS_INV_FLOATS (64 * 9)
#define WS_PART_OFFSET (WS_INV_FLOATS * sizeof(float))

__global__ void photoloss_invert_kernel(const float* __restrict__ Hp,
                                        const float* __restrict__ Ht,
                                        float* __restrict__ ws_inv) {
    int t = threadIdx.x;
    if (t < 64) {
        const float* src = (t < 32) ? (Hp + t * 9) : (Ht + (t - 32) * 9);
        float* dst = ws_inv + t * 9;
        // 3x3 inverse via adjugate, computed in double for conditioning.
        double a = src[0], b = src[1], c = src[2];
        double d = src[3], e = src[4], f = src[5];
        double g = src[6], h = src[7], i = src[8];
        double A = e * i - f * h;
        double Bc = c * h - b * i;
        double Cc = b * f - c * e;
        double D = f * g - d * i;
        double E = a * i - c * g;
        double F = c * d - a * f;
        double G = d * h - e * g;
        double Hh = b * g - a * h;
        double Ii = a * e - b * d;
        double idet = 1.0 / (a * A + b * D + c * G);
        // Fold the grid-normalization chain into rows 0/1:
        // xs = ((2X/(W-1)-1+1)*W-1)*0.5 = X*(W/(W-1)) - 0.5
        const double sc = (double)IMG_W / (double)(IMG_W - 1);  // 512/511 (H==W)
        dst[0] = (float)(A * idet * sc);
        dst[1] = (float)(Bc * idet * sc);
        dst[2] = (float)(Cc * idet * sc);
        dst[3] = (float)(D * idet * sc);
        dst[4] = (float)(E * idet * sc);
        dst[5] = (float)(F * idet * sc);
        dst[6] = (float)(G * idet);
        dst[7] = (float)(Hh * idet);
        dst[8] = (float)(Ii * idet);
    }
}

// Shared "front" of the sampling setup: source coords and floor cell.
// Identical arithmetic for fast and slow tails (bitwise same results).
__device__ __forceinline__ void setup_front(float X, float Y, float Z,
                                            float* xs, float* ys,
                                            float* x0f, float* y0f,
                                            int* x0, int* y0) {
    const float iz = __builtin_amdgcn_rcpf(Z);
    *xs = __builtin_fmaf(X, iz, -0.5f);
    *ys = __builtin_fmaf(Y, iz, -0.5f);
    *x0f = __builtin_floorf(*xs);
    *y0f = __builtin_floorf(*ys);
    *x0 = (int)(*x0f);
    *y0 = (int)(*y0f);
}

// Slow tail == R12's grid_setup_pair remainder, verbatim semantics.
// E[0]/E[1] = clamped element indices of the (y0,y1) row pairs.
// W[0..3]  = weights for (row0.slotA, row0.slotB, row1.slotA, row1.slotB).
// Validity lives ONLY in the weights. Two slot-swap cases:
//  - left edge x0==-1: pair loaded at xc0=0, x1 corner sits in slot A.
//  - clamp-down e==H*W-1 (image corner): x0 corner sits in slot B.
__device__ __forceinline__ void setup_tail_slow(float xs, float ys,
                                                float x0f, float y0f,
                                                int x0, int y0,
                                                int* E, float* W) {
    const int x1 = x0 + 1, y1 = y0 + 1;

    float wx1 = xs - x0f, wx0 = 1.0f - wx1;
    float wy1 = ys - y0f, wy0 = 1.0f - wy1;
    const float wx0m = ((unsigned)x0 < (unsigned)IMG_W) ? wx0 : 0.0f;
    const float wx1m = ((unsigned)x1 < (unsigned)IMG_W) ? wx1 : 0.0f;
    const float wy0m = ((unsigned)y0 < (unsigned)IMG_H) ? wy0 : 0.0f;
    const float wy1m = ((unsigned)y1 < (unsigned)IMG_H) ? wy1 : 0.0f;

    const bool sl = (x0 < 0);               // x0==-1 => x1 corner in slot A
    const float xA = sl ? wx1m : wx0m;      // (x0<=-2 => wx1m==0 too)
    const float xB = sl ? 0.0f : wx1m;
    const int xc0 = min(max(x0, 0), IMG_W - 1);

    const int e0r = y0 * IMG_W + xc0;       // may be far out of range
    const int e1r = e0r + IMG_W;
    const int emax = IMG_H * IMG_W - 2;     // pair [emax, emax+1] is last valid
    const int e0 = min(max(e0r, 0), emax);
    const int e1 = min(max(e1r, 0), emax);
    // Clamp fired? Either y-invalid (y-weight 0, slots irrelevant) or the
    // genuine e==H*W-1 corner case (clamp-down by 1: x0 value in slot B).
    const bool d0 = (e0 != e0r);
    const bool d1 = (e1 != e1r);
    const float uA0 = d0 ? 0.0f : xA, uB0 = d0 ? xA : xB;
    const float uA1 = d1 ? 0.0f : xA, uB1 = d1 ? xA : xB;

    E[0] = e0;
    E[1] = e1;
    W[0] = uA0 * wy0m; W[1] = uB0 * wy0m;
    W[2] = uA1 * wy1m; W[3] = uB1 * wy1m;
}

// Fast tail: interior-only (x0 in [0,W-2], y0 in [0,H-2]). No masks, no
// clamps, no slot swaps. Weight products in the SAME op order as the slow
// tail (uA0*wy0m == wx0*wy0 etc.) -> bit-identical weights.
__device__ __forceinline__ void setup_tail_fast(float xs, float ys,
                                                float x0f, float y0f,
                                                int x0, int y0,
                                                int* E, float* W) {
    const float wx1 = xs - x0f, wx0 = 1.0f - wx1;
    const float wy1 = ys - y0f, wy0 = 1.0f - wy1;
    const int e0 = (y0 << W_SHIFT) + x0;    // in [0, emax] by interior bound
    E[0] = e0;
    E[1] = e0 + IMG_W;
    W[0] = wx0 * wy0; W[1] = wx1 * wy0;
    W[2] = wx0 * wy1; W[3] = wx1 * wy1;
}

// 8-byte load at 4-byte alignment: memcpy -> load <2 x float> align 4 ->
// global_load_dwordx2 (gfx950 supports unaligned global access).
__device__ __forceinline__ float2 load_pair(const float* p) {
    float2 r;
    __builtin_memcpy(&r, p, 8);
    return r;
}

// 1 px/thread, one image row per 512-thread block.
__global__ __launch_bounds__(512) void photoloss_main_kernel(
        const float* __restrict__ I,
        const float* __restrict__ ws_inv,
        float* __restrict__ partials) {
    const int b = blockIdx.y;
    const int row = blockIdx.x;            // one full image row per block
    const int t = threadIdx.x;             // = x
    const float fy = (float)row;
    const float fx = (float)t;

    const float* __restrict__ hp = ws_inv + b * 9;          // pred inverse (rows 0/1 pre-scaled)
    const float* __restrict__ ht = ws_inv + (b + 32) * 9;   // true inverse

    // y-dependent part of each homography row
    const float cxp = __builtin_fmaf(hp[1], fy, hp[2]);
    const float cyp = __builtin_fmaf(hp[4], fy, hp[5]);
    const float czp = __builtin_fmaf(hp[7], fy, hp[8]);
    const float cxt = __builtin_fmaf(ht[1], fy, ht[2]);
    const float cyt = __builtin_fmaf(ht[4], fy, ht[5]);
    const float czt = __builtin_fmaf(ht[7], fy, ht[8]);

    // Fronts for both homographies (shared by fast/slow tails).
    float xsp, ysp, x0fp, y0fp; int x0p, y0p;
    float xst, yst, x0ft, y0ft; int x0t, y0t;
    setup_front(__builtin_fmaf(hp[0], fx, cxp), __builtin_fmaf(hp[3], fx, cyp),
                __builtin_fmaf(hp[6], fx, czp), &xsp, &ysp, &x0fp, &y0fp, &x0p, &y0p);
    setup_front(__builtin_fmaf(ht[0], fx, cxt), __builtin_fmaf(ht[3], fx, cyt),
                __builtin_fmaf(ht[6], fx, czt), &xst, &yst, &x0ft, &y0ft, &x0t, &y0t);

    // Interior: the whole 2x2 footprint in-range for BOTH homographies.
    const bool interior =
        ((unsigned)x0p <= (unsigned)(IMG_W - 2)) && ((unsigned)y0p <= (unsigned)(IMG_H - 2)) &&
        ((unsigned)x0t <= (unsigned)(IMG_W - 2)) && ((unsigned)y0t <= (unsigned)(IMG_H - 2));

    const float* __restrict__ ch0 = I + ((size_t)b * IMG_C << HW_SHIFT);
    const float* __restrict__ ch1 = ch0 + ((size_t)1 << HW_SHIFT);
    const float* __restrict__ ch2 = ch0 + ((size_t)2 << HW_SHIFT);

    // Pairs: j=0 pred.y0, j=1 pred.y1 (Wc[0..3]); j=2 true.y0, j=3 true.y1
    // (Wc[4..7]).
    int E[4];
    float Wc[8];
    float2 r[12];

    if (__all(interior)) {
        // FAST PATH (wave-uniform): no edge machinery, unconditional loads.
        setup_tail_fast(xsp, ysp, x0fp, y0fp, x0p, y0p, E + 0, Wc + 0);
        setup_tail_fast(xst, yst, x0ft, y0ft, x0t, y0t, E + 2, Wc + 4);
#pragma unroll
        for (int j = 0; j < 4; ++j) {
            r[0 * 4 + j] = load_pair(ch0 + E[j]);
            r[1 * 4 + j] = load_pair(ch1 + E[j]);
            r[2 * 4 + j] = load_pair(ch2 + E[j]);
        }
    } else {
        // SLOW PATH: R12 verbatim (edge weights/slots/clamps + predicated
        // loads; EXEC-masked lanes generate NO TA requests -> fully-OOB
        // regions skip their loads).
        setup_tail_slow(xsp, ysp, x0fp, y0fp, x0p, y0p, E + 0, Wc + 0);
        setup_tail_slow(xst, yst, x0ft, y0ft, x0t, y0t, E + 2, Wc + 4);

        bool pr[4];
#pragma unroll
        for (int k = 0; k < 4; ++k)
            pr[k] = (Wc[2 * k] + Wc[2 * k + 1]) > 0.0f;

#pragma unroll
        for (int j = 0; j < 4; ++j) {
            float2 v0 = make_float2(0.0f, 0.0f);
            float2 v1 = v0;
            float2 v2 = v0;
            if (pr[j]) {
                v0 = load_pair(ch0 + E[j]);
                v1 = load_pair(ch1 + E[j]);
                v2 = load_pair(ch2 + E[j]);
            }
            r[0 * 4 + j] = v0;
            r[1 * 4 + j] = v1;
            r[2 * 4 + j] = v2;
        }
    }

    float lsum = 0.0f;
#pragma unroll
    for (int c = 0; c < IMG_C; ++c) {
        const float2* rc = r + c * 4;
        const float sp = rc[0].x * Wc[0] + rc[0].y * Wc[1] + rc[1].x * Wc[2] + rc[1].y * Wc[3];
        const float st = rc[2].x * Wc[4] + rc[2].y * Wc[5] + rc[3].x * Wc[6] + rc[3].y * Wc[7];
        const float d = sp - st;
        lsum = __builtin_fmaf(d, d, lsum);
    }

    // wave (64-lane) reduction
#pragma unroll
    for (int off = 32; off > 0; off >>= 1)
        lsum += __shfl_down(lsum, off, 64);

    __shared__ float wsum[8];
    const int lane = threadIdx.x & 63;
    const int wid = threadIdx.x >> 6;
    if (lane == 0) wsum[wid] = lsum;
    __syncthreads();
    if (threadIdx.x == 0) {
        // One coalesced store per block -- NO atomics (same-address fp64
        // atomicAdd serialized the whole grid at ~400 us in R1/R2).
        float s = 0.0f;
#pragma unroll
        for (int i = 0; i < 8; ++i) s += wsum[i];
        partials[blockIdx.y * gridDim.x + blockIdx.x] = s;
    }
}

__global__ __launch_bounds__(1024) void photoloss_reduce_kernel(
        const float* __restrict__ partials, float* __restrict__ out) {
    // Single block, 1024 threads = 16 waves; 16 partials per thread.
    double s = 0.0;
    for (int i = threadIdx.x; i < NPARTIALS; i += 1024)
        s += (double)partials[i];
#pragma unroll
    for (int off = 32; off > 0; off >>= 1)
        s += __shfl_down(s, off, 64);

    __shared__ double wsum[16];
    const int lane = threadIdx.x & 63;
    const int wid = threadIdx.x >> 6;
    if (lane == 0) wsum[wid] = s;
    __syncthreads();
    if (threadIdx.x == 0) {
        double total = 0.0;
#pragma unroll
        for (int i = 0; i < 16; ++i) total += wsum[i];
        const double n = (double)IMG_B * IMG_C * IMG_H * IMG_W;  // 25165824
        out[0] = (float)(total / n);
    }
}

extern "C" void kernel_launch(void* const* d_in, const int* in_sizes, int n_in,
                              void* d_out, int out_size, void* d_ws, size_t ws_size,
                              hipStream_t stream) {
    const float* Hp = (const float*)d_in[0];
    const float* Ht = (const float*)d_in[1];
    const float* I  = (const float*)d_in[2];
    float* out = (float*)d_out;

    float* ws_inv = (float*)d_ws;
    float* partials = (float*)((char*)d_ws + WS_PART_OFFSET);

    photoloss_invert_kernel<<<1, 64, 0, stream>>>(Hp, Ht, ws_inv);

    dim3 grid(NBLOCKS_X, IMG_B);  // (512, 32), natural order (R6 XCD swizzle regressed)
    photoloss_main_kernel<<<grid, 512, 0, stream>>>(I, ws_inv, partials);

    photoloss_reduce_kernel<<<1, 1024, 0, stream>>>(partials, out);
}